// Round 1
// baseline (140.814 us; speedup 1.0000x reference)
//
#include <hip/hip_runtime.h>

#define N_NODES 50000
#define K_DEG   17
#define DIN     128
#define DOUT    64

// ---------------------------------------------------------------------------
// Batcher merge-exchange sorting network (Knuth TAOCP Alg. M), generated at
// compile time so indices constant-fold after full unroll (registers only).
// ---------------------------------------------------------------------------
struct CEPair { unsigned char a, b; };

constexpr int net_count(int n) {
  int t = 0; while ((1 << t) < n) ++t;
  int cnt = 0;
  for (int p = 1 << (t - 1); p > 0; p >>= 1) {
    int q = 1 << (t - 1), r = 0, d = p;
    for (;;) {
      for (int i = 0; i < n - d; ++i)
        if ((i & p) == r) ++cnt;
      if (q == p) break;
      d = q - p; q >>= 1; r = p;
    }
  }
  return cnt;
}

template <int NP>
struct NetArr { CEPair v[NP]; };

template <int NP>
constexpr NetArr<NP> net_pairs(int n) {
  NetArr<NP> out{};
  int t = 0; while ((1 << t) < n) ++t;
  int cnt = 0;
  for (int p = 1 << (t - 1); p > 0; p >>= 1) {
    int q = 1 << (t - 1), r = 0, d = p;
    for (;;) {
      for (int i = 0; i < n - d; ++i)
        if ((i & p) == r) {
          out.v[cnt].a = (unsigned char)i;
          out.v[cnt].b = (unsigned char)(i + d);
          ++cnt;
        }
      if (q == p) break;
      d = q - p; q >>= 1; r = p;
    }
  }
  return out;
}

constexpr int NP17 = net_count(K_DEG);   // 74 compare-exchanges for n=17

// ---------------------------------------------------------------------------
// Kernel 1: xp = x @ W   (fp32 vector GEMM, W staged in LDS)
// block 256 = 16 dim-groups x 16 row-groups; thread tile = 4 dims x 4 rows
// ---------------------------------------------------------------------------
__global__ __launch_bounds__(256) void gemm_kernel(
    const float* __restrict__ x, const float* __restrict__ W,
    float* __restrict__ xp) {
  __shared__ float Wl[DIN * DOUT];
  {
    const float4* Wg4 = (const float4*)W;
    float4* Wl4 = (float4*)Wl;
    #pragma unroll
    for (int i = 0; i < (DIN * DOUT / 4) / 256; ++i)
      Wl4[threadIdx.x + i * 256] = Wg4[threadIdx.x + i * 256];
  }
  __syncthreads();

  const int t  = threadIdx.x;
  const int d0 = (t & 15) * 4;        // 4 consecutive output dims
  const int rg = t >> 4;              // row group 0..15
  const int r0 = blockIdx.x * 64 + rg * 4;

  float4 acc[4];
  #pragma unroll
  for (int rr = 0; rr < 4; ++rr) acc[rr] = make_float4(0.f, 0.f, 0.f, 0.f);

  int rbase[4];
  #pragma unroll
  for (int rr = 0; rr < 4; ++rr) {
    int r = r0 + rr;
    rbase[rr] = (r < N_NODES ? r : N_NODES - 1) * (DIN / 4);
  }

  const float4* x4 = (const float4*)x;
  for (int kc = 0; kc < DIN / 4; ++kc) {
    float4 xv[4];
    #pragma unroll
    for (int rr = 0; rr < 4; ++rr) xv[rr] = x4[rbase[rr] + kc];
    #pragma unroll
    for (int kk = 0; kk < 4; ++kk) {
      float4 wv = *(const float4*)&Wl[(kc * 4 + kk) * DOUT + d0];
      #pragma unroll
      for (int rr = 0; rr < 4; ++rr) {
        float xs = (kk == 0) ? xv[rr].x : (kk == 1) ? xv[rr].y
                 : (kk == 2) ? xv[rr].z : xv[rr].w;
        acc[rr].x += xs * wv.x;
        acc[rr].y += xs * wv.y;
        acc[rr].z += xs * wv.z;
        acc[rr].w += xs * wv.w;
      }
    }
  }
  #pragma unroll
  for (int rr = 0; rr < 4; ++rr) {
    int r = r0 + rr;
    if (r < N_NODES) *(float4*)&xp[r * DOUT + d0] = acc[rr];
  }
}

// ---------------------------------------------------------------------------
// Kernel 2: per-node per-dim weighted median + row_sum scale + bias.
// One wave per node; lane = output dim (coalesced 256B gathers of xp rows).
// Numerics replicate the reference exactly: cumsum in ascending sorted
// order, total = last cum (sorted order), row_sum = original edge order.
// ---------------------------------------------------------------------------
__global__ __launch_bounds__(256) void median_kernel(
    const float* __restrict__ xp, const int* __restrict__ col,
    const float* __restrict__ ew, const float* __restrict__ bias,
    float* __restrict__ out) {
  const int wave = threadIdx.x >> 6;
  const int lane = threadIdx.x & 63;
  const int node = blockIdx.x * 4 + wave;
  if (node >= N_NODES) return;

  const int*   cp = col + node * K_DEG;
  const float* wp = ew  + node * K_DEG;

  float v[K_DEG], w[K_DEG];
  #pragma unroll
  for (int j = 0; j < K_DEG; ++j) {
    int c = cp[j];                    // wave-uniform -> scalarized
    v[j] = xp[c * DOUT + lane];       // 256B coalesced gather
    w[j] = wp[j];
  }

  // row_sum: original edge order (matches segment_sum)
  float rs = 0.f;
  #pragma unroll
  for (int j = 0; j < K_DEG; ++j) rs += w[j];

  // sort (v,w) pairs by v ascending — compile-time Batcher network
  constexpr NetArr<NP17> NET = net_pairs<NP17>(K_DEG);
  #pragma unroll
  for (int s = 0; s < NP17; ++s) {
    const int a = NET.v[s].a, b = NET.v[s].b;
    float va = v[a], vb = v[b];
    bool sw = vb < va;
    float wa = w[a], wb = w[b];
    v[a] = sw ? vb : va;  v[b] = sw ? va : vb;
    w[a] = sw ? wb : wa;  w[b] = sw ? wa : wb;
  }

  // total = cum[-1] in sorted order (exactly as reference cumsum)
  float tot = 0.f;
  #pragma unroll
  for (int j = 0; j < K_DEG; ++j) tot += w[j];
  const float half = 0.5f * tot;

  // first sorted position with cum >= half
  float cum = 0.f, med = 0.f;
  bool found = false;
  #pragma unroll
  for (int j = 0; j < K_DEG; ++j) {
    cum += w[j];
    bool ge  = (cum >= half);
    bool hit = ge && !found;
    med   = hit ? v[j] : med;
    found = found || ge;
  }

  out[node * DOUT + lane] = rs * med + bias[lane];
}

// ---------------------------------------------------------------------------
extern "C" void kernel_launch(void* const* d_in, const int* in_sizes, int n_in,
                              void* d_out, int out_size, void* d_ws, size_t ws_size,
                              hipStream_t stream) {
  const float* x    = (const float*)d_in[0];
  const int*   ei   = (const int*)d_in[1];
  const float* ew   = (const float*)d_in[2];
  const float* W    = (const float*)d_in[3];
  const float* bias = (const float*)d_in[4];
  float*       out  = (float*)d_out;
  float*       xp   = (float*)d_ws;               // 50000*64*4 = 12.8 MB
  const int*   colp = ei + (size_t)N_NODES * K_DEG;  // edge_index[1]

  gemm_kernel<<<(N_NODES + 63) / 64, 256, 0, stream>>>(x, W, xp);
  median_kernel<<<(N_NODES + 3) / 4, 256, 0, stream>>>(xp, colp, ew, bias, out);
}